// Round 7
// baseline (34269.635 us; speedup 1.0000x reference)
//
#include <hip/hip_runtime.h>
#include <hip/hip_bf16.h>
#include <hip/hip_cooperative_groups.h>
#include <math.h>

namespace cg = cooperative_groups;

#define BB 128
#define TT 512
#define U  512
#define G  2048   // 4*U

typedef short short8 __attribute__((ext_vector_type(8)));
typedef float floatx4 __attribute__((ext_vector_type(4)));

__device__ __forceinline__ float sigmoidf_(float x) {
    return 1.0f / (1.0f + __expf(-x));
}
__device__ __forceinline__ float tanhf_(float v) {
    float e = __expf(2.0f * v);
    return 1.0f - 2.0f / (e + 1.0f);
}

// ---------------- prep: Wh [512][2048] -> WhPT [d][c][k] bf16, c = u*4+g ----
__global__ __launch_bounds__(256)
void prep_wh(const float* __restrict__ Wh_f, const float* __restrict__ Wh_b,
             __hip_bfloat16* __restrict__ WhPT)
{
    const int kt = blockIdx.x, ct = blockIdx.y, d = blockIdx.z;
    const float* Wh = d ? Wh_b : Wh_f;
    const int tx = threadIdx.x & 31, ty = threadIdx.x >> 5;
    __shared__ float tile[32][33];
    #pragma unroll
    for (int i = 0; i < 4; ++i) {
        int r = ty + 8 * i;
        tile[r][tx] = Wh[(size_t)(kt * 32 + r) * G + ct * 32 + tx];
    }
    __syncthreads();
    #pragma unroll
    for (int i = 0; i < 4; ++i) {
        int colLocal = ty + 8 * i;
        int col = ct * 32 + colLocal;             // original col: g*512+u
        int c = ((col & 511) << 2) | (col >> 9);  // u*4+g
        WhPT[((size_t)d * G + c) * U + kt * 32 + tx] =
            __float2bfloat16(tile[tx][colLocal]);
    }
}

// ---------------- prep: WxbP [d][4][c] fp32 (rows 0..2 = Wx, row 3 = bias) --
__global__ __launch_bounds__(256)
void prep_wxb(const float* __restrict__ Wx_f, const float* __restrict__ b_f,
              const float* __restrict__ Wx_b, const float* __restrict__ b_b,
              float* __restrict__ WxbP)
{
    int idx = blockIdx.x * blockDim.x + threadIdx.x;
    if (idx >= 2 * G) return;
    int d = idx / G, c = idx % G;
    const float* Wx = d ? Wx_b : Wx_f;
    const float* bb = d ? b_b  : b_f;
    int col = ((c & 3) << 9) | (c >> 2);               // g*512+u
    WxbP[((size_t)d * 4 + 0) * G + c] = Wx[0 * G + col];
    WxbP[((size_t)d * 4 + 1) * G + c] = Wx[1 * G + col];
    WxbP[((size_t)d * 4 + 2) * G + c] = Wx[2 * G + col];
    WxbP[((size_t)d * 4 + 3) * G + c] = bb[col];
}

// ---------------- init: zero h (both phases, bf16) and c (fp32) ------------
__global__ void init_state(__hip_bfloat16* h, float* c, int nh, int nc)
{
    int i = blockIdx.x * blockDim.x + threadIdx.x;
    if (i < nh) h[i] = __float2bfloat16(0.0f);
    if (i < nc) c[i] = 0.0f;
}

// ================= persistent cooperative kernel ===========================
// grid: 512 WGs x 256 threads = 2048 waves (2 waves/SIMD @ 2 WG/CU)
// WG wg: dir = wg>>8, row-tile rt = (wg>>5)&7 (16 rows), col-group cgp = wg&31
//        (64 permuted cols = 16 units). Wave w: 16 permuted cols.
// B (Wh) fragments live in VGPRs for all 512 steps. c/h state in registers.
__global__ __launch_bounds__(256, 2)
void lstm_persistent(const float* __restrict__ x,       // [BB][TT][3]
                     const int*   __restrict__ mask,    // [BB][TT]
                     const __hip_bfloat16* __restrict__ WhPT,  // [2][G][U]
                     const float* __restrict__ WxbP,    // [2][4][G]
                     __hip_bfloat16* __restrict__ hbuf, // [2 phase][2][BB][U]
                     const float* __restrict__ W1,      // [U][4]
                     const float* __restrict__ b1,      // [4]
                     float* __restrict__ out)
{
    cg::grid_group grid = cg::this_grid();

    const int wg  = blockIdx.x;
    const int d   = wg >> 8;
    const int rt  = (wg >> 5) & 7;
    const int cgp = wg & 31;
    const int tid = threadIdx.x;
    const int w   = tid >> 6;          // wave 0..3
    const int l   = tid & 63;

    // ---- persistent B fragments: 16 x short8 = 64 VGPRs ----
    const short* Bp = (const short*)(WhPT + (size_t)d * G * U);
    const int bcol = cgp * 64 + w * 16 + (l & 15);   // permuted col
    const int kofs = (l >> 4) * 8;
    short8 bf[16];
    #pragma unroll
    for (int kk = 0; kk < 16; ++kk)
        bf[kk] = *(const short8*)(Bp + (size_t)bcol * U + kk * 32 + kofs);

    // ---- epilogue thread mapping: row = tid>>4, unit-local = tid&15 ----
    const int erow = tid >> 4;
    const int eul  = tid & 15;
    const int eb   = rt * 16 + erow;       // batch row
    const int eu   = cgp * 16 + eul;       // global unit

    const float* WxbD = WxbP + (size_t)d * 4 * G;
    const int c4 = cgp * 64 + eul * 4;
    const floatx4 wx0 = *(const floatx4*)(WxbD + 0 * G + c4);
    const floatx4 wx1 = *(const floatx4*)(WxbD + 1 * G + c4);
    const floatx4 wx2 = *(const floatx4*)(WxbD + 2 * G + c4);
    const floatx4 wb  = *(const floatx4*)(WxbD + 3 * G + c4);

    const int arow = rt * 16 + (l & 15);

    __shared__ float z[16][68];

    float c_reg = 0.0f, h_reg = 0.0f;

    float* sh = out + (size_t)BB * TT * 1024;   // state_h [BB][2][U]
    float* sc = sh + (size_t)BB * 2 * U;        // state_c [BB][2][U]
    float* pa = sc + (size_t)BB * 2 * U;        // pos_agg [BB][8]

    const int PH = 2 * BB * U;

    for (int t = 0; t < TT; ++t) {
        const int tau = d ? (TT - 1 - t) : t;
        const short* A =
            (const short*)(hbuf + (size_t)(t & 1) * PH + (size_t)d * BB * U);
        __hip_bfloat16* hn =
            hbuf + (size_t)((t + 1) & 1) * PH + (size_t)d * BB * U;

        // A fragments then MFMA (loads issued in a batch for pipelining)
        short8 af[16];
        #pragma unroll
        for (int kk = 0; kk < 16; ++kk)
            af[kk] = *(const short8*)(A + (size_t)arow * U + kk * 32 + kofs);

        floatx4 acc = {0.f, 0.f, 0.f, 0.f};
        #pragma unroll
        for (int kk = 0; kk < 16; ++kk)
            acc = __builtin_amdgcn_mfma_f32_16x16x32_bf16(af[kk], bf[kk], acc, 0, 0, 0);

        // C layout: col = lane&15, row = (lane>>4)*4 + reg
        {
            int rl = (l >> 4) * 4;
            int cl = w * 16 + (l & 15);
            #pragma unroll
            for (int j = 0; j < 4; ++j) z[rl + j][cl] = acc[j];
        }
        __syncthreads();

        // epilogue: one (row, unit) per thread
        floatx4 zz = *(const floatx4*)&z[erow][eul * 4];
        const float* xr = x + ((size_t)eb * TT + tau) * 3;
        float x0 = xr[0], x1 = xr[1], x2 = xr[2];

        float zi = zz[0] + x0 * wx0[0] + x1 * wx1[0] + x2 * wx2[0] + wb[0];
        float zf = zz[1] + x0 * wx0[1] + x1 * wx1[1] + x2 * wx2[1] + wb[1];
        float zg = zz[2] + x0 * wx0[2] + x1 * wx1[2] + x2 * wx2[2] + wb[2];
        float zo = zz[3] + x0 * wx0[3] + x1 * wx1[3] + x2 * wx2[3] + wb[3];

        float ig = sigmoidf_(zi);
        float fg = sigmoidf_(zf);
        float gg = tanhf_(zg);
        float og = sigmoidf_(zo);

        float cn = fg * c_reg + ig * gg;
        float hv = og * tanhf_(cn);
        bool  m  = (mask[(size_t)eb * TT + tau] != 0);
        float h2 = m ? hv : h_reg;
        float c2 = m ? cn : c_reg;
        h_reg = h2;
        c_reg = c2;

        hn[(size_t)eb * U + eu] = __float2bfloat16(h2);           // 32B/16-lane
        out[((size_t)eb * TT + tau) * 1024 + d * 512 + eu] = h2;  // 64B/16-lane

        grid.sync();   // h(t+1) visible everywhere; also block barrier for z
    }

    // final states from registers (exact fp32)
    sh[(size_t)eb * 1024 + d * 512 + eu] = h_reg;
    sc[(size_t)eb * 1024 + d * 512 + eu] = c_reg;

    grid.sync();

    // pos_agg: first 128 WGs, one batch row each; read fp32 state_h
    if (wg < BB) {
        const int b = wg;
        __shared__ float red[8][8];
        if (tid < 64) {
            int j = tid & 7, seg = tid >> 3;
            int jj = j & 3;
            const float* hv = sh + (size_t)b * 1024 + (j >> 2) * 512;
            float s = 0.f;
            for (int u = seg * 64; u < seg * 64 + 64; ++u)
                s = fmaf(hv[u], W1[u * 4 + jj], s);
            red[seg][j] = s;
        }
        __syncthreads();
        if (tid < 8) {
            float s = b1[tid & 3];
            #pragma unroll
            for (int seg = 0; seg < 8; ++seg) s += red[seg][tid];
            pa[b * 8 + tid] = s;
        }
    }
}

// ================= fallback path (proven R4): per-step kernel ==============
__global__ __launch_bounds__(64)
void lstm_step(const float* __restrict__ x,
               const int*   __restrict__ mask,
               const __hip_bfloat16* __restrict__ WhPT,
               const float* __restrict__ WxbP,
               const __hip_bfloat16* __restrict__ hr,
               __hip_bfloat16*       __restrict__ hw,
               float*       __restrict__ cws,
               float*       __restrict__ out,
               int t)
{
    const int ct = blockIdx.x;
    const int rt = blockIdx.y;
    const int d  = blockIdx.z;
    const int l  = threadIdx.x;
    const int tau = d ? (TT - 1 - t) : t;

    const short* A  = (const short*)(hr + (size_t)d * BB * U);
    const short* Bp = (const short*)(WhPT + (size_t)d * G * U);
    const int r0 = rt * 16;
    const int c0 = ct * 32;

    const int arow = r0 + (l & 15);
    const int kofs = (l >> 4) * 8;
    const int bc0  = c0 + (l & 15);

    floatx4 acc0 = {0.f, 0.f, 0.f, 0.f};
    floatx4 acc1 = {0.f, 0.f, 0.f, 0.f};

    #pragma unroll
    for (int kk = 0; kk < 16; ++kk) {
        int k = kk * 32 + kofs;
        short8 a  = *(const short8*)(A  + (size_t)arow * U + k);
        short8 b0 = *(const short8*)(Bp + (size_t)bc0        * U + k);
        short8 b1 = *(const short8*)(Bp + (size_t)(bc0 + 16) * U + k);
        acc0 = __builtin_amdgcn_mfma_f32_16x16x32_bf16(a, b0, acc0, 0, 0, 0);
        acc1 = __builtin_amdgcn_mfma_f32_16x16x32_bf16(a, b1, acc1, 0, 0, 0);
    }

    __shared__ float z[16][36];
    {
        int rl = (l >> 4) * 4;
        int cl = l & 15;
        #pragma unroll
        for (int j = 0; j < 4; ++j) {
            z[rl + j][cl]      = acc0[j];
            z[rl + j][cl + 16] = acc1[j];
        }
    }
    __syncthreads();

    const float* WxbD = WxbP + (size_t)d * 4 * G;
    #pragma unroll
    for (int p = 0; p < 2; ++p) {
        int row = l & 15;
        int un  = (l >> 4) + 4 * p;
        int b   = r0 + row;
        int u   = ct * 8 + un;
        int c4  = c0 + un * 4;

        floatx4 zz  = *(const floatx4*)&z[row][un * 4];
        floatx4 wx0 = *(const floatx4*)(WxbD + 0 * G + c4);
        floatx4 wx1 = *(const floatx4*)(WxbD + 1 * G + c4);
        floatx4 wx2 = *(const floatx4*)(WxbD + 2 * G + c4);
        floatx4 wb  = *(const floatx4*)(WxbD + 3 * G + c4);

        const float* xr = x + ((size_t)b * TT + tau) * 3;
        float x0 = xr[0], x1 = xr[1], x2 = xr[2];

        float zi = zz[0] + x0 * wx0[0] + x1 * wx1[0] + x2 * wx2[0] + wb[0];
        float zf = zz[1] + x0 * wx0[1] + x1 * wx1[1] + x2 * wx2[1] + wb[1];
        float zg = zz[2] + x0 * wx0[2] + x1 * wx1[2] + x2 * wx2[2] + wb[2];
        float zo = zz[3] + x0 * wx0[3] + x1 * wx1[3] + x2 * wx2[3] + wb[3];

        float ig = sigmoidf_(zi);
        float fg = sigmoidf_(zf);
        float gg = tanhf_(zg);
        float og = sigmoidf_(zo);

        size_t su = (size_t)d * BB * U + (size_t)b * U + u;
        float cprev = cws[su];
        float hprev = __bfloat162float(hr[su]);
        float cn = fg * cprev + ig * gg;
        float hn = og * tanhf_(cn);
        bool  m  = (mask[(size_t)b * TT + tau] != 0);
        float h2 = m ? hn : hprev;
        float c2 = m ? cn : cprev;
        cws[su] = c2;
        hw[su]  = __float2bfloat16(h2);
        out[((size_t)b * TT + tau) * 1024 + d * 512 + u] = h2;
    }
}

__global__ __launch_bounds__(256)
void finalize(const __hip_bfloat16* __restrict__ hfin,
              const float* __restrict__ cfin,
              const float* __restrict__ W1,
              const float* __restrict__ b1,
              float* __restrict__ out)
{
    const int b = blockIdx.x;
    const int tid = threadIdx.x;
    float* sh = out + (size_t)BB * TT * 1024;
    float* sc = sh + (size_t)BB * 2 * U;
    float* pa = sc + (size_t)BB * 2 * U;
    for (int i = tid; i < 2 * U; i += 256) {
        int d = i / U, u = i % U;
        sh[(size_t)b * 2 * U + i] = __bfloat162float(hfin[(size_t)d * BB * U + b * U + u]);
        sc[(size_t)b * 2 * U + i] = cfin[(size_t)d * BB * U + b * U + u];
    }
    __shared__ float red[8][8];
    if (tid < 64) {
        int j = tid & 7;
        int seg = tid >> 3;
        int dd = j >> 2, jj = j & 3;
        const __hip_bfloat16* hv = hfin + (size_t)dd * BB * U + (size_t)b * U;
        float s = 0.f;
        for (int u = seg * 64; u < seg * 64 + 64; ++u)
            s = fmaf(__bfloat162float(hv[u]), W1[u * 4 + jj], s);
        red[seg][j] = s;
    }
    __syncthreads();
    if (tid < 8) {
        float s = b1[tid & 3];
        #pragma unroll
        for (int seg = 0; seg < 8; ++seg) s += red[seg][tid];
        pa[b * 8 + tid] = s;
    }
}

extern "C" void kernel_launch(void* const* d_in, const int* in_sizes, int n_in,
                              void* d_out, int out_size, void* d_ws, size_t ws_size,
                              hipStream_t stream)
{
    (void)in_sizes; (void)n_in; (void)out_size; (void)ws_size;
    const float* x    = (const float*)d_in[0];
    const int*   mask = (const int*)d_in[1];
    const float* Wx_f = (const float*)d_in[2];
    const float* Wh_f = (const float*)d_in[3];
    const float* b_f  = (const float*)d_in[4];
    const float* Wx_b = (const float*)d_in[5];
    const float* Wh_b = (const float*)d_in[6];
    const float* b_b  = (const float*)d_in[7];
    const float* W1   = (const float*)d_in[8];
    const float* b1   = (const float*)d_in[9];
    float* out = (float*)d_out;

    char* wsb = (char*)d_ws;
    __hip_bfloat16* WhPT = (__hip_bfloat16*)wsb;                 wsb += (size_t)2 * G * U * 2;
    float*          WxbP = (float*)wsb;                          wsb += (size_t)2 * 4 * G * 4;
    __hip_bfloat16* hbuf = (__hip_bfloat16*)wsb;                 wsb += (size_t)2 * 2 * BB * U * 2;
    float*          cbuf = (float*)wsb;

    const int PH = 2 * BB * U;

    prep_wh<<<dim3(16, 64, 2), 256, 0, stream>>>(Wh_f, Wh_b, WhPT);
    prep_wxb<<<(2 * G + 255) / 256, 256, 0, stream>>>(Wx_f, b_f, Wx_b, b_b, WxbP);
    init_state<<<(2 * PH + 255) / 256, 256, 0, stream>>>(hbuf, cbuf, 2 * PH, PH);

    // ---- preferred: single persistent cooperative kernel ----
    {
        const float* xa = x; const int* ma = mask;
        const __hip_bfloat16* wh = WhPT; const float* wx = WxbP;
        __hip_bfloat16* hb = hbuf; const float* w1 = W1; const float* bb1 = b1;
        float* oo = out;
        void* args[] = { (void*)&xa, (void*)&ma, (void*)&wh, (void*)&wx,
                         (void*)&hb, (void*)&w1, (void*)&bb1, (void*)&oo };
        hipError_t err = hipLaunchCooperativeKernel(
            (const void*)lstm_persistent, dim3(512), dim3(256), args, 0, stream);
        if (err == hipSuccess) return;
        (void)hipGetLastError();   // clear error, fall through to fallback
    }

    // ---- fallback: proven per-step loop (R4) ----
    dim3 grid(64, 8, 2), block(64);
    for (int t = 0; t < TT; ++t) {
        const __hip_bfloat16* hrp = hbuf + (size_t)(t & 1) * PH;
        __hip_bfloat16*       hwp = hbuf + (size_t)((t + 1) & 1) * PH;
        lstm_step<<<grid, block, 0, stream>>>(x, mask, WhPT, WxbP,
                                              hrp, hwp, cbuf, out, t);
    }
    finalize<<<BB, 256, 0, stream>>>(hbuf, cbuf, W1, b1, out);
}

// Round 8
// 6768.224 us; speedup vs baseline: 5.0633x; 5.0633x over previous
//
#include <hip/hip_runtime.h>
#include <hip/hip_bf16.h>
#include <math.h>

#define BB 128
#define TT 512
#define U  512
#define G  2048   // 4*U

typedef short short8 __attribute__((ext_vector_type(8)));
typedef float floatx4 __attribute__((ext_vector_type(4)));

__device__ __forceinline__ float sigmoidf_(float x) {
    return 1.0f / (1.0f + __expf(-x));
}
__device__ __forceinline__ float tanhf_(float v) {
    float e = __expf(2.0f * v);
    return 1.0f - 2.0f / (e + 1.0f);
}

// ---------------- prep: Wh [512][2048] -> WhPT [d][c][k] bf16, c = u*4+g ----
__global__ __launch_bounds__(256)
void prep_wh(const float* __restrict__ Wh_f, const float* __restrict__ Wh_b,
             __hip_bfloat16* __restrict__ WhPT)
{
    const int kt = blockIdx.x, ct = blockIdx.y, d = blockIdx.z;
    const float* Wh = d ? Wh_b : Wh_f;
    const int tx = threadIdx.x & 31, ty = threadIdx.x >> 5;
    __shared__ float tile[32][33];
    #pragma unroll
    for (int i = 0; i < 4; ++i) {
        int r = ty + 8 * i;
        tile[r][tx] = Wh[(size_t)(kt * 32 + r) * G + ct * 32 + tx];
    }
    __syncthreads();
    #pragma unroll
    for (int i = 0; i < 4; ++i) {
        int colLocal = ty + 8 * i;
        int col = ct * 32 + colLocal;             // original col: g*512+u
        int c = ((col & 511) << 2) | (col >> 9);  // u*4+g
        WhPT[((size_t)d * G + c) * U + kt * 32 + tx] =
            __float2bfloat16(tile[tx][colLocal]);
    }
}

// ---------------- prep: WxbP [d][4][c] fp32 (rows 0..2 = Wx, row 3 = bias) --
__global__ __launch_bounds__(256)
void prep_wxb(const float* __restrict__ Wx_f, const float* __restrict__ b_f,
              const float* __restrict__ Wx_b, const float* __restrict__ b_b,
              float* __restrict__ WxbP)
{
    int idx = blockIdx.x * blockDim.x + threadIdx.x;
    if (idx >= 2 * G) return;
    int d = idx / G, c = idx % G;
    const float* Wx = d ? Wx_b : Wx_f;
    const float* bb = d ? b_b  : b_f;
    int col = ((c & 3) << 9) | (c >> 2);               // g*512+u
    WxbP[((size_t)d * 4 + 0) * G + c] = Wx[0 * G + col];
    WxbP[((size_t)d * 4 + 1) * G + c] = Wx[1 * G + col];
    WxbP[((size_t)d * 4 + 2) * G + c] = Wx[2 * G + col];
    WxbP[((size_t)d * 4 + 3) * G + c] = bb[col];
}

// ---------------- init: zero h (both phases, bf16) and c (fp32) ------------
__global__ void init_state(__hip_bfloat16* h, float* c, int nh, int nc)
{
    int i = blockIdx.x * blockDim.x + threadIdx.x;
    if (i < nh) h[i] = __float2bfloat16(0.0f);
    if (i < nc) c[i] = 0.0f;
}

// ---------------- one step: 16-col tiles, 2048 WGs (2 waves/SIMD) ----------
// grid (128 col-tiles of 16, 8 row-tiles of 16, 2 dirs), block 64 (1 wave)
// Per wave: 16 A-loads + 16 B-loads (16B each, L2-resident) + 16 MFMAs.
__global__ __launch_bounds__(64)
void lstm_step(const float* __restrict__ x,       // [BB][TT][3]
               const int*   __restrict__ mask,    // [BB][TT]
               const __hip_bfloat16* __restrict__ WhPT,  // [2][G][U]
               const float* __restrict__ WxbP,    // [2][4][G]
               const __hip_bfloat16* __restrict__ hr,    // [2][BB][U] read
               __hip_bfloat16*       __restrict__ hw,    // [2][BB][U] write
               float*       __restrict__ cws,     // [2][BB][U]
               float*       __restrict__ out,     // [BB][TT][1024]
               int t)
{
    const int ct = blockIdx.x;            // 16 permuted cols = 4 units
    const int rt = blockIdx.y;            // 16 rows
    const int d  = blockIdx.z;
    const int l  = threadIdx.x;           // 0..63
    const int tau = d ? (TT - 1 - t) : t;

    const short* A  = (const short*)(hr + (size_t)d * BB * U);
    const short* Bp = (const short*)(WhPT + (size_t)d * G * U);
    const int r0 = rt * 16;
    const int c0 = ct * 16;

    const int arow = r0 + (l & 15);
    const int kofs = (l >> 4) * 8;
    const int bcol = c0 + (l & 15);

    floatx4 acc = {0.f, 0.f, 0.f, 0.f};

    #pragma unroll
    for (int kk = 0; kk < 16; ++kk) {
        int k = kk * 32 + kofs;
        short8 a = *(const short8*)(A  + (size_t)arow * U + k);
        short8 b = *(const short8*)(Bp + (size_t)bcol * U + k);
        acc = __builtin_amdgcn_mfma_f32_16x16x32_bf16(a, b, acc, 0, 0, 0);
    }

    // C layout: col = lane&15, row = (lane>>4)*4 + reg
    __shared__ float z[16][20];
    {
        int rl = (l >> 4) * 4;
        int cl = l & 15;
        #pragma unroll
        for (int j = 0; j < 4; ++j) z[rl + j][cl] = acc[j];
    }
    __syncthreads();

    // epilogue: one (row, unit) per lane: row = l&15, local unit = l>>4
    {
        const int row = l & 15;
        const int un  = l >> 4;              // 0..3
        const int b   = r0 + row;
        const int u   = ct * 4 + un;         // global unit
        const int c4  = c0 + un * 4;         // permuted col of gate 0

        const float* WxbD = WxbP + (size_t)d * 4 * G;
        floatx4 zz  = *(const floatx4*)&z[row][un * 4];
        floatx4 wx0 = *(const floatx4*)(WxbD + 0 * G + c4);
        floatx4 wx1 = *(const floatx4*)(WxbD + 1 * G + c4);
        floatx4 wx2 = *(const floatx4*)(WxbD + 2 * G + c4);
        floatx4 wb  = *(const floatx4*)(WxbD + 3 * G + c4);

        const float* xr = x + ((size_t)b * TT + tau) * 3;
        float x0 = xr[0], x1 = xr[1], x2 = xr[2];

        float zi = zz[0] + x0 * wx0[0] + x1 * wx1[0] + x2 * wx2[0] + wb[0];
        float zf = zz[1] + x0 * wx0[1] + x1 * wx1[1] + x2 * wx2[1] + wb[1];
        float zg = zz[2] + x0 * wx0[2] + x1 * wx1[2] + x2 * wx2[2] + wb[2];
        float zo = zz[3] + x0 * wx0[3] + x1 * wx1[3] + x2 * wx2[3] + wb[3];

        float ig = sigmoidf_(zi);
        float fg = sigmoidf_(zf);
        float gg = tanhf_(zg);
        float og = sigmoidf_(zo);

        size_t su = (size_t)d * BB * U + (size_t)b * U + u;
        float cprev = cws[su];
        float hprev = __bfloat162float(hr[su]);
        float cn = fg * cprev + ig * gg;
        float hn = og * tanhf_(cn);
        bool  m  = (mask[(size_t)b * TT + tau] != 0);
        float h2 = m ? hn : hprev;
        float c2 = m ? cn : cprev;
        cws[su] = c2;
        hw[su]  = __float2bfloat16(h2);
        out[((size_t)b * TT + tau) * 1024 + d * 512 + u] = h2;
    }
}

// ---------------- finalize: states + pos_agg -------------------------------
__global__ __launch_bounds__(256)
void finalize(const __hip_bfloat16* __restrict__ hfin,
              const float* __restrict__ cfin,
              const float* __restrict__ W1,
              const float* __restrict__ b1,
              float* __restrict__ out)
{
    const int b = blockIdx.x;
    const int tid = threadIdx.x;
    float* sh = out + (size_t)BB * TT * 1024;
    float* sc = sh + (size_t)BB * 2 * U;
    float* pa = sc + (size_t)BB * 2 * U;
    for (int i = tid; i < 2 * U; i += 256) {
        int d = i / U, u = i % U;
        sh[(size_t)b * 2 * U + i] = __bfloat162float(hfin[(size_t)d * BB * U + b * U + u]);
        sc[(size_t)b * 2 * U + i] = cfin[(size_t)d * BB * U + b * U + u];
    }
    __shared__ float red[8][8];
    if (tid < 64) {
        int j = tid & 7;
        int seg = tid >> 3;
        int dd = j >> 2, jj = j & 3;
        const __hip_bfloat16* hv = hfin + (size_t)dd * BB * U + (size_t)b * U;
        float s = 0.f;
        for (int u = seg * 64; u < seg * 64 + 64; ++u)
            s = fmaf(__bfloat162float(hv[u]), W1[u * 4 + jj], s);
        red[seg][j] = s;
    }
    __syncthreads();
    if (tid < 8) {
        float s = b1[tid & 3];
        #pragma unroll
        for (int seg = 0; seg < 8; ++seg) s += red[seg][tid];
        pa[b * 8 + tid] = s;
    }
}

extern "C" void kernel_launch(void* const* d_in, const int* in_sizes, int n_in,
                              void* d_out, int out_size, void* d_ws, size_t ws_size,
                              hipStream_t stream)
{
    (void)in_sizes; (void)n_in; (void)out_size; (void)ws_size;
    const float* x    = (const float*)d_in[0];
    const int*   mask = (const int*)d_in[1];
    const float* Wx_f = (const float*)d_in[2];
    const float* Wh_f = (const float*)d_in[3];
    const float* b_f  = (const float*)d_in[4];
    const float* Wx_b = (const float*)d_in[5];
    const float* Wh_b = (const float*)d_in[6];
    const float* b_b  = (const float*)d_in[7];
    const float* W1   = (const float*)d_in[8];
    const float* b1   = (const float*)d_in[9];
    float* out = (float*)d_out;

    char* wsb = (char*)d_ws;
    __hip_bfloat16* WhPT = (__hip_bfloat16*)wsb;                 wsb += (size_t)2 * G * U * 2;
    float*          WxbP = (float*)wsb;                          wsb += (size_t)2 * 4 * G * 4;
    __hip_bfloat16* hbuf = (__hip_bfloat16*)wsb;                 wsb += (size_t)2 * 2 * BB * U * 2;
    float*          cbuf = (float*)wsb;

    const int PH = 2 * BB * U;

    prep_wh<<<dim3(16, 64, 2), 256, 0, stream>>>(Wh_f, Wh_b, WhPT);
    prep_wxb<<<(2 * G + 255) / 256, 256, 0, stream>>>(Wx_f, b_f, Wx_b, b_b, WxbP);
    init_state<<<(2 * PH + 255) / 256, 256, 0, stream>>>(hbuf, cbuf, 2 * PH, PH);

    dim3 grid(128, 8, 2), block(64);
    for (int t = 0; t < TT; ++t) {
        const __hip_bfloat16* hrp = hbuf + (size_t)(t & 1) * PH;
        __hip_bfloat16*       hwp = hbuf + (size_t)((t + 1) & 1) * PH;
        lstm_step<<<grid, block, 0, stream>>>(x, mask, WhPT, WxbP,
                                              hrp, hwp, cbuf, out, t);
    }
    finalize<<<BB, 256, 0, stream>>>(hbuf, cbuf, W1, b1, out);
}